// Round 2
// baseline (201.523 us; speedup 1.0000x reference)
//
#include <hip/hip_runtime.h>
#include <math.h>

// RepulsionLoss: B=8, N=4096, 3D points, k=4 NN (skip self), H=0.03
// loss = sum over all queries/neighbors of -d * exp(-d / H^2)

#define NB    8
#define NPTS  4096
#define INV_H2 1111.1111111111111f   // 1 / (0.03*0.03)
#define BIG   3.402823466e+38f

// ---------------- prep: pack (x,y,z) -> float4 for 16B coalesced loads ---------
__global__ __launch_bounds__(256) void prep_kernel(const float* __restrict__ pc,
                                                   float4* __restrict__ pts4) {
    int i = blockIdx.x * 256 + threadIdx.x;
    if (i < NB * NPTS) {
        float x = pc[3 * i + 0];
        float y = pc[3 * i + 1];
        float z = pc[3 * i + 2];
        pts4[i] = make_float4(x, y, z, 0.0f);
    }
}

// ---------------- main: 8 lanes per query, top-5 per lane, butterfly merge ------
// block = 256 threads = 4 waves; each wave handles 8 queries (8 lanes each).
// grid = NB * (NPTS/32) = 1024 blocks.
__global__ __launch_bounds__(256) void knn_kernel(const float4* __restrict__ pts4,
                                                  float* __restrict__ partials) {
    const int tid  = threadIdx.x;
    const int lane = tid & 63;
    const int wid  = tid >> 6;
    const int qg   = lane >> 3;   // query slot within wave: 0..7
    const int s    = lane & 7;    // scan subset: 0..7

    const int b    = blockIdx.x >> 7;          // 128 blocks per batch
    const int qblk = (blockIdx.x & 127) * 32;  // 32 queries per block
    const int iq   = qblk + wid * 8 + qg;

    const float4* __restrict__ base = pts4 + b * NPTS;
    const float4 qp = base[iq];
    const float qx = qp.x, qy = qp.y, qz = qp.z;

    // sorted ascending top-5 smallest distances (d0 <= ... <= d4)
    float d0 = BIG, d1 = BIG, d2 = BIG, d3 = BIG, d4 = BIG;

    // lane s scans j = t*8 + s; each wave-iteration touches one 128B line,
    // broadcast across the wave's 8 query groups -> L1-resident.
    const float4* __restrict__ p = base + s;
    #pragma unroll 4
    for (int t = 0; t < NPTS / 8; ++t) {
        float4 v = p[t * 8];
        float dx = v.x - qx;
        float dy = v.y - qy;
        float dz = v.z - qz;
        float dd = fmaf(dz, dz, fmaf(dy, dy, dx * dx));
        int j = t * 8 + s;
        dd = (j == iq) ? BIG : dd;           // mask self-match
        if (dd < d4) {                        // rare after warmup
            d4 = dd;
            float u;
            u = fminf(d3, d4); d4 = fmaxf(d3, d4); d3 = u;
            u = fminf(d2, d3); d3 = fmaxf(d2, d3); d2 = u;
            u = fminf(d1, d2); d2 = fmaxf(d1, d2); d1 = u;
            u = fminf(d0, d1); d1 = fmaxf(d0, d1); d0 = u;
        }
    }

    // merge the 8 subsets' sorted top-5 lists (xor butterfly over low 3 lane bits)
    #pragma unroll
    for (int m = 1; m <= 4; m <<= 1) {
        float e0 = __shfl_xor(d0, m);
        float e1 = __shfl_xor(d1, m);
        float e2 = __shfl_xor(d2, m);
        float e3 = __shfl_xor(d3, m);
        float e4 = __shfl_xor(d4, m);
        float u;
        d4 = fminf(d4, e0);
        u = fminf(d3, d4); d4 = fmaxf(d3, d4); d3 = u;
        u = fminf(d2, d3); d3 = fmaxf(d2, d3); d2 = u;
        u = fminf(d1, d2); d2 = fmaxf(d1, d2); d1 = u;
        u = fminf(d0, d1); d1 = fmaxf(d0, d1); d0 = u;
        d4 = fminf(d4, e1);
        u = fminf(d3, d4); d4 = fmaxf(d3, d4); d3 = u;
        u = fminf(d2, d3); d3 = fmaxf(d2, d3); d2 = u;
        u = fminf(d1, d2); d2 = fmaxf(d1, d2); d1 = u;
        u = fminf(d0, d1); d1 = fmaxf(d0, d1); d0 = u;
        d4 = fminf(d4, e2);
        u = fminf(d3, d4); d4 = fmaxf(d3, d4); d3 = u;
        u = fminf(d2, d3); d3 = fmaxf(d2, d3); d2 = u;
        u = fminf(d1, d2); d2 = fmaxf(d1, d2); d1 = u;
        u = fminf(d0, d1); d1 = fmaxf(d0, d1); d0 = u;
        d4 = fminf(d4, e3);
        u = fminf(d3, d4); d4 = fmaxf(d3, d4); d3 = u;
        u = fminf(d2, d3); d3 = fmaxf(d2, d3); d2 = u;
        u = fminf(d1, d2); d2 = fmaxf(d1, d2); d1 = u;
        u = fminf(d0, d1); d1 = fmaxf(d0, d1); d0 = u;
        d4 = fminf(d4, e4);
        u = fminf(d3, d4); d4 = fmaxf(d3, d4); d3 = u;
        u = fminf(d2, d3); d3 = fmaxf(d2, d3); d2 = u;
        u = fminf(d1, d2); d2 = fmaxf(d1, d2); d1 = u;
        u = fminf(d0, d1); d1 = fmaxf(d0, d1); d0 = u;
    }

    // Self was masked to BIG, so d0..d3 are the 4 true NN distances.
    float lsum = 0.0f;
    if (s == 0) {
        lsum = d0 * __expf(-d0 * INV_H2)
             + d1 * __expf(-d1 * INV_H2)
             + d2 * __expf(-d2 * INV_H2)
             + d3 * __expf(-d3 * INV_H2);
        lsum = -lsum;
    }

    // wave reduce (lanes with s!=0 hold 0)
    #pragma unroll
    for (int m = 32; m >= 1; m >>= 1) lsum += __shfl_xor(lsum, m);

    __shared__ float wsum[4];
    if (lane == 0) wsum[wid] = lsum;
    __syncthreads();
    if (tid == 0) partials[blockIdx.x] = wsum[0] + wsum[1] + wsum[2] + wsum[3];
}

// ---------------- final reduction of 1024 block partials -----------------------
__global__ __launch_bounds__(256) void reduce_kernel(const float* __restrict__ partials,
                                                     float* __restrict__ out) {
    int tid = threadIdx.x;
    float v = partials[tid] + partials[tid + 256] + partials[tid + 512] + partials[tid + 768];
    #pragma unroll
    for (int m = 32; m >= 1; m >>= 1) v += __shfl_xor(v, m);
    __shared__ float ws[4];
    if ((tid & 63) == 0) ws[tid >> 6] = v;
    __syncthreads();
    if (tid == 0) out[0] = ws[0] + ws[1] + ws[2] + ws[3];
}

extern "C" void kernel_launch(void* const* d_in, const int* in_sizes, int n_in,
                              void* d_out, int out_size, void* d_ws, size_t ws_size,
                              hipStream_t stream) {
    const float* pc = (const float*)d_in[0];
    float* out = (float*)d_out;

    float4* pts4    = (float4*)d_ws;
    float* partials = (float*)((char*)d_ws + (size_t)NB * NPTS * sizeof(float4));

    prep_kernel<<<(NB * NPTS + 255) / 256, 256, 0, stream>>>(pc, pts4);
    knn_kernel<<<NB * (NPTS / 32), 256, 0, stream>>>(pts4, partials);
    reduce_kernel<<<1, 256, 0, stream>>>(partials, out);
}

// Round 3
// 119.190 us; speedup vs baseline: 1.6908x; 1.6908x over previous
//
#include <hip/hip_runtime.h>
#include <math.h>

// RepulsionLoss: B=8, N=4096, 3D points, k=4 NN (skip self), H=0.03
// loss = sum_q sum_{4NN} -d * exp(-d / H^2)
//
// Round-3 design: branchless top-5 (parallel sorted-insert, 9 min/max),
// gram-form distance (|p|^2 packed in float4.w -> 4 VALU/pair),
// self-match kept (computes to ~0, dropped as d0 after merge),
// 16 lanes per query -> 8192 waves (8/SIMD nominal) for latency hiding.

#define NB     8
#define NPTS   4096
#define INV_H2 1111.1111111111111f   // 1 / (0.03*0.03)
#define BIG    1e30f
#define SPLIT  16                     // lanes per query

// parallel branchless insert of 'e' into sorted ascending d0..d4
#define INSERT5(e)                          \
    do {                                    \
        float _m0 = fmaxf(d0, (e));         \
        float _m1 = fmaxf(d1, (e));         \
        float _m2 = fmaxf(d2, (e));         \
        float _m3 = fmaxf(d3, (e));         \
        d0 = fminf(d0, (e));                \
        d1 = fminf(d1, _m0);                \
        d2 = fminf(d2, _m1);                \
        d3 = fminf(d3, _m2);                \
        d4 = fminf(d4, _m3);                \
    } while (0)

// ---------------- prep: (x,y,z) -> (x,y,z,|p|^2) ------------------------------
__global__ __launch_bounds__(256) void prep_kernel(const float* __restrict__ pc,
                                                   float4* __restrict__ pts4) {
    int i = blockIdx.x * 256 + threadIdx.x;
    if (i < NB * NPTS) {
        float x = pc[3 * i + 0];
        float y = pc[3 * i + 1];
        float z = pc[3 * i + 2];
        float n = fmaf(x, x, fmaf(y, y, z * z));
        pts4[i] = make_float4(x, y, z, n);
    }
}

// ---------------- main: 16 lanes/query, branchless top-5, butterfly merge ------
// block = 256 threads = 4 waves; each wave: 4 queries x 16 scan-lanes.
// grid = NB * 256 = 2048 blocks (16 queries per block).
__global__ __launch_bounds__(256, 8) void knn_kernel(const float4* __restrict__ pts4,
                                                     float* __restrict__ partials) {
    const int tid  = threadIdx.x;
    const int lane = tid & 63;
    const int wid  = tid >> 6;
    const int qg   = lane >> 4;   // query slot within wave: 0..3
    const int s    = lane & 15;   // scan subset: 0..15

    const int b  = blockIdx.x >> 8;                           // 256 blocks per batch
    const int iq = ((blockIdx.x & 255) << 4) + (wid << 2) + qg;

    const float4* __restrict__ base = pts4 + b * NPTS;
    const float4 qp = base[iq];
    const float nqx = -2.0f * qp.x;
    const float nqy = -2.0f * qp.y;
    const float nqz = -2.0f * qp.z;
    const float Cq  = qp.w;       // |q|^2

    // sorted ascending top-5 smallest (self ~0 will end up in d0)
    float d0 = BIG, d1 = BIG, d2 = BIG, d3 = BIG, d4 = BIG;

    // lane s scans j = t*16 + s: 16 consecutive float4 (256B) per wave-iter,
    // broadcast across the 4 query groups -> L1/L2 resident.
    const float4* __restrict__ p = base + s;
    #pragma unroll 4
    for (int t = 0; t < NPTS / SPLIT; ++t) {
        float4 v = p[t * SPLIT];
        float acc = v.w + Cq;             // |p|^2 + |q|^2
        acc = fmaf(v.x, nqx, acc);        // - 2 p.q
        acc = fmaf(v.y, nqy, acc);
        acc = fmaf(v.z, nqz, acc);
        INSERT5(acc);
    }

    // merge the 16 subsets' sorted top-5 lists (xor butterfly over low 4 bits)
    #pragma unroll
    for (int m = 1; m <= 8; m <<= 1) {
        float e0 = __shfl_xor(d0, m);
        float e1 = __shfl_xor(d1, m);
        float e2 = __shfl_xor(d2, m);
        float e3 = __shfl_xor(d3, m);
        float e4 = __shfl_xor(d4, m);
        INSERT5(e0);
        INSERT5(e1);
        INSERT5(e2);
        INSERT5(e3);
        INSERT5(e4);
    }

    // d0 == self (~0); d1..d4 are the 4 true NN squared distances.
    float lsum = 0.0f;
    if (s == 0) {
        float e1 = fmaxf(d1, 0.0f);
        float e2 = fmaxf(d2, 0.0f);
        float e3 = fmaxf(d3, 0.0f);
        float e4 = fmaxf(d4, 0.0f);
        lsum = e1 * __expf(-e1 * INV_H2)
             + e2 * __expf(-e2 * INV_H2)
             + e3 * __expf(-e3 * INV_H2)
             + e4 * __expf(-e4 * INV_H2);
        lsum = -lsum;
    }

    // wave reduce (lanes with s!=0 hold 0)
    #pragma unroll
    for (int m = 32; m >= 1; m >>= 1) lsum += __shfl_xor(lsum, m);

    __shared__ float wsum[4];
    if (lane == 0) wsum[wid] = lsum;
    __syncthreads();
    if (tid == 0) partials[blockIdx.x] = wsum[0] + wsum[1] + wsum[2] + wsum[3];
}

// ---------------- final reduction of 2048 block partials -----------------------
__global__ __launch_bounds__(256) void reduce_kernel(const float* __restrict__ partials,
                                                     float* __restrict__ out) {
    int tid = threadIdx.x;
    float v = 0.0f;
    #pragma unroll
    for (int i = 0; i < 8; ++i) v += partials[tid + 256 * i];
    #pragma unroll
    for (int m = 32; m >= 1; m >>= 1) v += __shfl_xor(v, m);
    __shared__ float ws[4];
    if ((tid & 63) == 0) ws[tid >> 6] = v;
    __syncthreads();
    if (tid == 0) out[0] = ws[0] + ws[1] + ws[2] + ws[3];
}

extern "C" void kernel_launch(void* const* d_in, const int* in_sizes, int n_in,
                              void* d_out, int out_size, void* d_ws, size_t ws_size,
                              hipStream_t stream) {
    const float* pc = (const float*)d_in[0];
    float* out = (float*)d_out;

    float4* pts4    = (float4*)d_ws;
    float* partials = (float*)((char*)d_ws + (size_t)NB * NPTS * sizeof(float4));

    prep_kernel<<<(NB * NPTS + 255) / 256, 256, 0, stream>>>(pc, pts4);
    knn_kernel<<<NB * 256, 256, 0, stream>>>(pts4, partials);
    reduce_kernel<<<1, 256, 0, stream>>>(partials, out);
}